// Round 11
// baseline (198.501 us; speedup 1.0000x reference)
//
#include <hip/hip_runtime.h>
#include <math.h>

#define T_SEQ 2048
#define NB 2
#define NH 16
#define DH 64
#define DM 1024

typedef unsigned short u16;
typedef __attribute__((ext_vector_type(8))) __bf16 bf16x8;
typedef __attribute__((ext_vector_type(4))) __bf16 bf16v4;
typedef __attribute__((ext_vector_type(4))) short s16x4;
typedef __attribute__((ext_vector_type(4))) float f32x4;
typedef __attribute__((ext_vector_type(4))) int i32x4;

// Native RNE convert: compiles to v_cvt_pk_bf16_f32 (paired by the compiler).
__device__ __forceinline__ u16 f2bf(float f) {
  return __builtin_bit_cast(u16, (__bf16)f);
}
__device__ __forceinline__ float bf2f(u16 v) {
  unsigned u = ((unsigned)v) << 16;
  return __builtin_bit_cast(float, u);
}
// Aliasing-safe vector moves (memcpy: no TBAA tag; emits b128/b64/dwordx4)
__device__ __forceinline__ bf16x8 ld_frag(const u16* p) {
  bf16x8 r; __builtin_memcpy(&r, p, 16); return r;
}
__device__ __forceinline__ s16x4 ld8(const u16* p) {
  s16x4 r; __builtin_memcpy(&r, p, 8); return r;
}
__device__ __forceinline__ i32x4 ld16(const u16* p) {
  i32x4 r; __builtin_memcpy(&r, p, 16); return r;
}
__device__ __forceinline__ void st16(u16* p, i32x4 v) {
  __builtin_memcpy(p, &v, 16);
}
// Load 8 f32, convert RNE -> 8 bf16 (v_cvt_pk_bf16_f32 x4), store 16B.
__device__ __forceinline__ void cvt_store8(u16* dst, const float* src) {
  f32x4 a, b;
  __builtin_memcpy(&a, src, 16);
  __builtin_memcpy(&b, src + 4, 16);
  bf16x8 t;
  t[0] = (__bf16)a[0]; t[1] = (__bf16)a[1]; t[2] = (__bf16)a[2]; t[3] = (__bf16)a[3];
  t[4] = (__bf16)b[0]; t[5] = (__bf16)b[1]; t[6] = (__bf16)b[2]; t[7] = (__bf16)b[3];
  __builtin_memcpy(dst, &t, 16);
}
// Async 16B global -> LDS (direct DMA, no VGPR round trip).
__device__ __forceinline__ void gld_lds16(const u16* g, u16* l) {
  __builtin_amdgcn_global_load_lds(
      (const __attribute__((address_space(1))) void*)g,
      (__attribute__((address_space(3))) void*)l, 16, 0, 0);
}

// f32 -> bf16 elementwise (8 elems/thread)
__global__ __launch_bounds__(256) void cvt_f32_bf16(const float* __restrict__ in,
                                                    u16* __restrict__ out, int n8) {
  const int i = blockIdx.x * 256 + threadIdx.x;
  if (i < n8) cvt_store8(out + (long)i * 8, in + (long)i * 8);
}

// R18 fallback: fused dual-tensor convert (x and qkv_w).
__global__ __launch_bounds__(256) void cvt2_f32_bf16(
    const float* __restrict__ inA, u16* __restrict__ outA, int n8A,
    const float* __restrict__ inB, u16* __restrict__ outB, int n8B,
    int blocksA) {
  if ((int)blockIdx.x < blocksA) {
    const int i = blockIdx.x * 256 + threadIdx.x;
    if (i < n8A) cvt_store8(outA + (long)i * 8, inA + (long)i * 8);
  } else {
    const int i = (blockIdx.x - blocksA) * 256 + threadIdx.x;
    if (i < n8B) cvt_store8(outB + (long)i * 8, inB + (long)i * 8);
  }
}

// R22: fused triple-tensor convert (x, qkv_w, proj_w) — one front dispatch.
__global__ __launch_bounds__(256) void cvt3_f32_bf16(
    const float* __restrict__ inA, u16* __restrict__ outA, int n8A,
    const float* __restrict__ inB, u16* __restrict__ outB, int n8B,
    const float* __restrict__ inC, u16* __restrict__ outC, int n8C,
    int bA, int bB) {
  const int bx = blockIdx.x, tid = threadIdx.x;
  if (bx < bA) {
    const int i = bx * 256 + tid;
    if (i < n8A) cvt_store8(outA + (long)i * 8, inA + (long)i * 8);
  } else if (bx < bA + bB) {
    const int i = (bx - bA) * 256 + tid;
    if (i < n8B) cvt_store8(outB + (long)i * 8, inB + (long)i * 8);
  } else {
    const int i = (bx - bA - bB) * 256 + tid;
    if (i < n8C) cvt_store8(outC + (long)i * 8, inC + (long)i * 8);
  }
}

// ---------------------------------------------------------------------------
// NT GEMM, m97-style: A,B bf16, global_load_lds w=16, unpadded LDS,
// BM x BN tile, 2-barrier K-loop.
// R23: BM templated. gemm0 (qkv): BM=64, BN=128 -> grid (24,64) = 1536
// blocks = 6/CU (R21 counters: gemm0 occupancy 15%, both pipes <30%,
// 4x off both rooflines = latency-starved at 3 blk/CU; BM-halving doubles
// resident blocks WITHOUT touching VGPR budget or the dh/dh+32 RoPE wave
// pairing, which pins BN=128). Per-wave: acc[BM/32][4], 3 staging loads.
// K-accumulation order per output unchanged -> bit-identical.
// gemm1 (proj): BM=128, BN=64 unchanged.
// Epilogue trig kept on-device (R21: table version SLOWER, scattered loads).
// MODE 0: scatter -> q,k [B][H][T][DH] with RoPE FUSED; V TRANSPOSED
//         [B][H][DH][T]. MODE 1: f32 row-major out.
// ---------------------------------------------------------------------------
template <int MODE, int BN, int BM>
__global__ __launch_bounds__(256) void gemm_nt(
    const u16* __restrict__ A, const u16* __restrict__ Bw,
    const float* __restrict__ bias, float* __restrict__ out,
    u16* __restrict__ q_ws, u16* __restrict__ k_ws, u16* __restrict__ v_ws,
    int M, int N, int K) {
  constexpr int NTN = BN / 32;          // n-tiles per wave (4 or 2)
  constexpr int WNS = BN / 2;           // per-wave n-span (64 or 32)
  constexpr int MT = BM / 32;           // m-tiles per wave (4 or 2)
  constexpr int WMS = BM / 2;           // per-wave m-span (64 or 32)
  __shared__ __align__(16) u16 As[BM * 32];
  __shared__ __align__(16) u16 Bs[BN * 32];
  const int tid = threadIdx.x;
  const int wave = tid >> 6, lane = tid & 63;
  const int quad = lane >> 4, l16 = lane & 15;
  const int wm = wave & 1, wn = wave >> 1;
  const int m0 = blockIdx.y * BM, n0 = blockIdx.x * BN;
  const int lrow = lane >> 2;           // 0..15
  const int lcol = (lane & 3) * 8;      // 8-elem chunk offset

  f32x4 acc[MT][NTN] = {};

  const u16* Ag = A + (long)(m0 + wave * 16 + lrow) * K + lcol;
  const u16* Bg = Bw + (long)(n0 + wave * 16 + lrow) * K + lcol;
  u16* Al = &As[(wave * 16 + lrow) * 32 + lcol];
  u16* Bl = &Bs[(wave * 16 + lrow) * 32 + lcol];

  for (int k0 = 0; k0 < K; k0 += 32) {
    __syncthreads();
    gld_lds16(Ag + k0, Al);
    if constexpr (BM == 128) gld_lds16(Ag + (long)64 * K + k0, Al + 64 * 32);
    gld_lds16(Bg + k0, Bl);
    if constexpr (BN == 128) gld_lds16(Bg + (long)64 * K + k0, Bl + 64 * 32);
    __syncthreads();
    bf16x8 af[MT], bfr[NTN];
#pragma unroll
    for (int mt = 0; mt < MT; mt++)
      af[mt] = ld_frag(&As[(wm * WMS + mt * 16 + l16) * 32 + quad * 8]);
#pragma unroll
    for (int nt = 0; nt < NTN; nt++)
      bfr[nt] = ld_frag(&Bs[(wn * WNS + nt * 16 + l16) * 32 + quad * 8]);
#pragma unroll
    for (int mt = 0; mt < MT; mt++)
#pragma unroll
      for (int nt = 0; nt < NTN; nt++)
        acc[mt][nt] = __builtin_amdgcn_mfma_f32_16x16x32_bf16(af[mt], bfr[nt],
                                                              acc[mt][nt], 0, 0, 0);
  }

  if constexpr (MODE == 1) {
#pragma unroll
    for (int nt = 0; nt < NTN; nt++) {
      const int col = n0 + wn * WNS + nt * 16 + l16;
      const float bv = bias[col];
#pragma unroll
      for (int mt = 0; mt < MT; mt++) {
        const int rbase = m0 + wm * WMS + mt * 16 + quad * 4;
#pragma unroll
        for (int r = 0; r < 4; r++)
          out[(long)(rbase + r) * N + col] = acc[mt][nt][r] + bv;
      }
    }
  } else {
    const int which = n0 >> 10;  // block-uniform: 0=q 1=k 2=v
#pragma unroll
    for (int np = 0; np < 2; np++) {  // pair (np, np+2): head-dims dh, dh+32
      const int col1 = n0 + wn * 64 + np * 16 + l16;
      const int rem = col1 & 1023;
      const int h = rem >> 6, dh = rem & 63;     // dh < 32 always
      const float bv1 = bias[col1], bv2 = bias[col1 + 32];
      if (which == 2) {  // V: no rope, transposed store [B][H][DH][T]
#pragma unroll
        for (int mt = 0; mt < MT; mt++) {
          const int rbase = m0 + wm * WMS + mt * 16 + quad * 4;
          const int b = rbase >> 11;
#pragma unroll
          for (int r = 0; r < 4; r++) {
            const int t = (rbase + r) & (T_SEQ - 1);
            const long vb = (((long)(b * NH + h)) * DH) * T_SEQ + t;
            v_ws[vb + (long)dh * T_SEQ] = f2bf(acc[mt][np][r] + bv1);
            v_ws[vb + (long)(dh + 32) * T_SEQ] = f2bf(acc[mt][np + 2][r] + bv2);
          }
        }
      } else {  // q or k: fused RoPE (+1/8 score scale folded into q)
        const float invf = exp2f(-(float)dh * 0.41524101186092045f);
        const float cD = cosf(invf), sD = sinf(invf);  // per-row angle step
        u16* dst = (which == 0) ? q_ws : k_ws;
        const float sc = (which == 0) ? 0.125f : 1.0f;
#pragma unroll
        for (int mt = 0; mt < MT; mt++) {
          const int rbase = m0 + wm * WMS + mt * 16 + quad * 4;
          const int b = rbase >> 11;
          const int t0 = rbase & (T_SEQ - 1);
          float c = cosf((float)t0 * invf), s = sinf((float)t0 * invf);
#pragma unroll
          for (int r = 0; r < 4; r++) {
            const float v1 = acc[mt][np][r] + bv1;
            const float v2 = acc[mt][np + 2][r] + bv2;
            const float o1 = (v1 * c - v2 * s) * sc;
            const float o2 = (v2 * c + v1 * s) * sc;
            const long ib = (((long)(b * NH + h)) * T_SEQ + (t0 + r)) * DH;
            dst[ib + dh] = f2bf(o1);
            dst[ib + dh + 32] = f2bf(o2);
            const float cn = c * cD - s * sD;   // advance angle by invf
            s = s * cD + c * sD;
            c = cn;
          }
        }
      }
    }
  }
}

// ---------------------------------------------------------------------------
// Flash attention (causal). R23 = R18 structure + Vt stride 136->140:
//  SQ_LDS_BANK_CONFLICT = 6.49M cy/dispatch (~20% of kernel cycles upper
//  bound). Bank math: Vt stride 136 elems = 68 dw = 4 (mod 32) -> the
//  16-row x 4-quad PV ds_read_b64 is ~4-way aliased and V-staging writes
//  ~8-way. Stride 140 = 70 dw = 6 (mod 32): period-16 bank walk, all 16
//  rows distinct -> ~2-way (free, m136). Cost: V rows 8B-aligned (staging
//  b128 -> 2x b64). Pure layout change, values identical.
//  Everything else frozen from R18 (best 50.5-51.2us): T5 setprio, T14
//  split staging, fixed-shift softmax, cvt_pk.
//  FAILED grafts (do not revisit): R15 32-row blocks; R17 de-LDS;
//  R19 512-thr 8-wave (spill); R20 grid key-split; R21 RoPE table.
// ---------------------------------------------------------------------------
__global__ __launch_bounds__(256, 4) void attn_kernel(const u16* __restrict__ q,
                                                      const u16* __restrict__ k,
                                                      const u16* __restrict__ v,
                                                      u16* __restrict__ o) {
  __shared__ __align__(16) u16 Ks[128 * 72];
  __shared__ __align__(16) u16 Vt[64 * 140];
  const int tid = threadIdx.x;
  const int wave = tid >> 6, lane = tid & 63;
  const int quad = lane >> 4, l16 = lane & 15;
  const int bh = blockIdx.x;     // 0..31  (XCD = const per bh)
  const int y = blockIdx.y;      // 0..31
  const int kk = y >> 3, a = y & 7;   // stride-8-proof complementary map
  const int qt = (kk == 0) ? (2 * a)
               : (kk == 1) ? (31 - 2 * a)
               : (kk == 2) ? (2 * a + 1)
                           : (30 - 2 * a);
  const long base = (long)bh * T_SEQ * DH;
  const int b = bh >> 4, h = bh & 15;

  const int q0 = qt * 64;
  const int qrow = q0 + wave * 16 + l16;   // this lane's q-row
  bf16x8 bq0, bq1;                         // Q as B-fragment
  {
    const u16* qr = q + base + (long)qrow * DH + quad * 8;
    bq0 = ld_frag(qr);
    bq1 = ld_frag(qr + 32);
  }
  float lst = 0.f;
  f32x4 oacc[4] = {};    // O^T: col=q(l16), row=d=ont*16+quad*4+r
  const int nkt = (q0 + 64 + 127) >> 7;    // 128-key staged tiles

  // staging geometry (lane-constant)
  const int k_rr = tid >> 3;          // + p*32, rows of K tile
  const int k_cc = (tid & 7) * 8;     // 16B col chunk
  const int v_d  = tid >> 4;          // + p*16, head-dim rows of V^T
  const int v_cc = (tid & 15) * 8;    // 16B col chunk along T
  const u16* kbase = k + base;
  const u16* vbase = v + base;

  i32x4 kreg[4], vreg[4];
  // prologue: load tile 0 into regs, write to LDS
#pragma unroll
  for (int p = 0; p < 4; p++) {
    kreg[p] = ld16(kbase + (long)(k_rr + p * 32) * DH + k_cc);
    vreg[p] = ld16(vbase + (long)(v_d + p * 16) * T_SEQ + v_cc);
  }
#pragma unroll
  for (int p = 0; p < 4; p++) {
    st16(&Ks[(k_rr + p * 32) * 72 + k_cc], kreg[p]);
    st16(&Vt[(v_d + p * 16) * 140 + v_cc], vreg[p]);
  }
  __syncthreads();

  for (int kt = 0; kt < nkt; kt++) {
    const int key0 = kt * 128;
    const bool last = (kt == nkt - 1);

    // T14(a): issue next tile's global loads NOW; latency hides under compute
    if (!last) {
      const int kn = key0 + 128;
#pragma unroll
      for (int p = 0; p < 4; p++) {
        kreg[p] = ld16(kbase + (long)kn * DH + (long)(k_rr + p * 32) * DH + k_cc);
        vreg[p] = ld16(vbase + kn + (long)(v_d + p * 16) * T_SEQ + v_cc);
      }
    }

#pragma unroll
    for (int hh = 0; hh < 2; hh++) {
      if (hh == 1 && last && key0 >= q0) continue;  // fully-masked half
      const int kb = key0 + hh * 64;

      // St sub-tile (batched): sfr[nt][r] = S[kb+nt*16+quad*4+r][qrow]
      f32x4 sfr[4];
      __builtin_amdgcn_s_setprio(1);   // T5: favor MFMA-phase waves
#pragma unroll
      for (int nt = 0; nt < 4; nt++) {
        const int row = hh * 64 + nt * 16 + l16;
        bf16x8 k0f = ld_frag(&Ks[row * 72 + quad * 8]);
        bf16x8 k1f = ld_frag(&Ks[row * 72 + 32 + quad * 8]);
        f32x4 z = {0.f, 0.f, 0.f, 0.f};
        z = __builtin_amdgcn_mfma_f32_16x16x32_bf16(k0f, bq0, z, 0, 0, 0);
        z = __builtin_amdgcn_mfma_f32_16x16x32_bf16(k1f, bq1, z, 0, 0, 0);
        sfr[nt] = z;
      }
      __builtin_amdgcn_s_setprio(0);

      if (last) {  // causal mask (diagonal staged tile only)
#pragma unroll
        for (int nt = 0; nt < 4; nt++) {
          const int keyb = kb + nt * 16 + quad * 4;
#pragma unroll
          for (int r = 0; r < 4; r++)
            sfr[nt][r] = (keyb + r <= qrow) ? sfr[nt][r] : -1e30f;
        }
      }

      // P^T = exp2(S*log2e - 46.166)  (fixed shift m=32; masked -> 0)
      float rsum = 0.f;
      s16x4 pf[4];
#pragma unroll
      for (int nt = 0; nt < 4; nt++) {
        bf16v4 pv;
#pragma unroll
        for (int r = 0; r < 4; r++) {
          const float p =
              exp2f(__builtin_fmaf(sfr[nt][r], 1.44269504f, -46.166241f));
          rsum += p;
          pv[r] = (__bf16)p;   // v_cvt_pk_bf16_f32 (RNE)
        }
        pf[nt] = __builtin_bit_cast(s16x4, pv);
      }
      rsum += __shfl_xor(rsum, 16, 64);
      rsum += __shfl_xor(rsum, 32, 64);
      lst += rsum;

      // O^T += V^T · P^T  (A-frag: Vt[d][k], 8B loads, ~2-way banks @140)
      __builtin_amdgcn_s_setprio(1);   // T5
#pragma unroll
      for (int ont = 0; ont < 4; ont++) {
        const u16* vrow = &Vt[(ont * 16 + l16) * 140 + hh * 64 + quad * 4];
#pragma unroll
        for (int nt = 0; nt < 4; nt++) {
          s16x4 vf = ld8(vrow + nt * 16);
          oacc[ont] = __builtin_amdgcn_mfma_f32_16x16x16bf16_1k(vf, pf[nt],
                                                                oacc[ont], 0, 0, 0);
        }
      }
      __builtin_amdgcn_s_setprio(0);
    }

    // T14(b): everyone done reading LDS -> overwrite with prefetched tile
    if (!last) {
      __syncthreads();
#pragma unroll
      for (int p = 0; p < 4; p++) {
        st16(&Ks[(k_rr + p * 32) * 72 + k_cc], kreg[p]);
        st16(&Vt[(v_d + p * 16) * 140 + v_cc], vreg[p]);
      }
      __syncthreads();
    }
  }

  // epilogue: O^T/l -> attn_out ws [B][T][C] bf16; 4 consecutive d per quad
  const float inv_l = 1.f / lst;
  u16* orow = o + ((long)(b * T_SEQ + qrow)) * DM + h * DH + quad * 4;
#pragma unroll
  for (int ont = 0; ont < 4; ont++) {
    bf16v4 t4;
#pragma unroll
    for (int r = 0; r < 4; r++) t4[r] = (__bf16)(oacc[ont][r] * inv_l);
    __builtin_memcpy(orow + ont * 16, &t4, 8);
  }
}

// ---------------------------------------------------------------------------
extern "C" void kernel_launch(void* const* d_in, const int* in_sizes, int n_in,
                              void* d_out, int out_size, void* d_ws, size_t ws_size,
                              hipStream_t stream) {
  const float* x      = (const float*)d_in[0];
  const float* qkv_w  = (const float*)d_in[1];
  const float* qkv_b  = (const float*)d_in[2];
  const float* proj_w = (const float*)d_in[3];
  const float* proj_b = (const float*)d_in[4];
  float* out = (float*)d_out;

  u16* ws = (u16*)d_ws;
  const long per = (long)NB * NH * T_SEQ * DH;  // 4,194,304 elems
  u16* q_ws = ws;
  u16* k_ws = ws + per;
  u16* v_ws = ws + 2 * per;              // transposed [B][H][DH][T]
  u16* ao_ws = ws + 3 * per;             // aliases x_bf (x dead after gemm0)
  u16* x_bf  = ws + 3 * per;
  u16* w_bf  = ws + 4 * per;             // qkv_w_bf (gemm0)
  const size_t base_bytes = (size_t)(4 * per + 3 * DM * DM) * 2;  // 39.85 MB
  u16* pw_bf = (u16*)((char*)d_ws + base_bytes);                  // 2 MB
  const size_t need = base_bytes + (size_t)DM * DM * 2;

  dim3 blk(256);
  if (ws_size >= need) {
    // R22 front: one kernel converts x, qkv_w, proj_w; no late cvt.
    cvt3_f32_bf16<<<2048 + 1536 + 512, blk, 0, stream>>>(
        x, x_bf, (int)(per / 8), qkv_w, w_bf, 3 * DM * DM / 8,
        proj_w, pw_bf, DM * DM / 8, 2048, 1536);
    gemm_nt<0, 128, 64><<<dim3(24, 64), blk, 0, stream>>>(
        x_bf, w_bf, qkv_b, nullptr, q_ws, k_ws, v_ws, 4096, 3072, 1024);
    attn_kernel<<<dim3(32, 32), blk, 0, stream>>>(q_ws, k_ws, v_ws, ao_ws);
    gemm_nt<1, 64, 128><<<dim3(16, 32), blk, 0, stream>>>(
        ao_ws, pw_bf, proj_b, out, nullptr, nullptr, nullptr, 4096, 1024, 1024);
  } else {
    // fallback (R18-style ordering)
    cvt2_f32_bf16<<<2048 + 1536, blk, 0, stream>>>(
        x, x_bf, (int)(per / 8), qkv_w, w_bf, 3 * DM * DM / 8, 2048);
    gemm_nt<0, 128, 64><<<dim3(24, 64), blk, 0, stream>>>(
        x_bf, w_bf, qkv_b, nullptr, q_ws, k_ws, v_ws, 4096, 3072, 1024);
    attn_kernel<<<dim3(32, 32), blk, 0, stream>>>(q_ws, k_ws, v_ws, ao_ws);
    cvt_f32_bf16<<<512, blk, 0, stream>>>(proj_w, w_bf, DM * DM / 8);
    gemm_nt<1, 64, 128><<<dim3(16, 32), blk, 0, stream>>>(
        ao_ws, w_bf, proj_b, out, nullptr, nullptr, nullptr, 4096, 1024, 1024);
  }
}

// Round 12
// 188.091 us; speedup vs baseline: 1.0553x; 1.0553x over previous
//
#include <hip/hip_runtime.h>
#include <math.h>

#define T_SEQ 2048
#define NB 2
#define NH 16
#define DH 64
#define DM 1024

typedef unsigned short u16;
typedef __attribute__((ext_vector_type(8))) __bf16 bf16x8;
typedef __attribute__((ext_vector_type(4))) __bf16 bf16v4;
typedef __attribute__((ext_vector_type(4))) short s16x4;
typedef __attribute__((ext_vector_type(4))) float f32x4;
typedef __attribute__((ext_vector_type(4))) int i32x4;

// Native RNE convert: compiles to v_cvt_pk_bf16_f32 (paired by the compiler).
__device__ __forceinline__ u16 f2bf(float f) {
  return __builtin_bit_cast(u16, (__bf16)f);
}
__device__ __forceinline__ float bf2f(u16 v) {
  unsigned u = ((unsigned)v) << 16;
  return __builtin_bit_cast(float, u);
}
// Aliasing-safe vector moves (memcpy: no TBAA tag; emits b128/b64/dwordx4)
__device__ __forceinline__ bf16x8 ld_frag(const u16* p) {
  bf16x8 r; __builtin_memcpy(&r, p, 16); return r;
}
__device__ __forceinline__ s16x4 ld8(const u16* p) {
  s16x4 r; __builtin_memcpy(&r, p, 8); return r;
}
__device__ __forceinline__ i32x4 ld16(const u16* p) {
  i32x4 r; __builtin_memcpy(&r, p, 16); return r;
}
__device__ __forceinline__ void st16(u16* p, i32x4 v) {
  __builtin_memcpy(p, &v, 16);
}
// Load 8 f32, convert RNE -> 8 bf16 (v_cvt_pk_bf16_f32 x4), store 16B.
__device__ __forceinline__ void cvt_store8(u16* dst, const float* src) {
  f32x4 a, b;
  __builtin_memcpy(&a, src, 16);
  __builtin_memcpy(&b, src + 4, 16);
  bf16x8 t;
  t[0] = (__bf16)a[0]; t[1] = (__bf16)a[1]; t[2] = (__bf16)a[2]; t[3] = (__bf16)a[3];
  t[4] = (__bf16)b[0]; t[5] = (__bf16)b[1]; t[6] = (__bf16)b[2]; t[7] = (__bf16)b[3];
  __builtin_memcpy(dst, &t, 16);
}
// Async 16B global -> LDS (direct DMA, no VGPR round trip).
__device__ __forceinline__ void gld_lds16(const u16* g, u16* l) {
  __builtin_amdgcn_global_load_lds(
      (const __attribute__((address_space(1))) void*)g,
      (__attribute__((address_space(3))) void*)l, 16, 0, 0);
}

// f32 -> bf16 elementwise (8 elems/thread)
__global__ __launch_bounds__(256) void cvt_f32_bf16(const float* __restrict__ in,
                                                    u16* __restrict__ out, int n8) {
  const int i = blockIdx.x * 256 + threadIdx.x;
  if (i < n8) cvt_store8(out + (long)i * 8, in + (long)i * 8);
}

// R18 fallback: fused dual-tensor convert (x and qkv_w).
__global__ __launch_bounds__(256) void cvt2_f32_bf16(
    const float* __restrict__ inA, u16* __restrict__ outA, int n8A,
    const float* __restrict__ inB, u16* __restrict__ outB, int n8B,
    int blocksA) {
  if ((int)blockIdx.x < blocksA) {
    const int i = blockIdx.x * 256 + threadIdx.x;
    if (i < n8A) cvt_store8(outA + (long)i * 8, inA + (long)i * 8);
  } else {
    const int i = (blockIdx.x - blocksA) * 256 + threadIdx.x;
    if (i < n8B) cvt_store8(outB + (long)i * 8, inB + (long)i * 8);
  }
}

// R22: fused triple-tensor convert (x, qkv_w, proj_w) — one front dispatch.
__global__ __launch_bounds__(256) void cvt3_f32_bf16(
    const float* __restrict__ inA, u16* __restrict__ outA, int n8A,
    const float* __restrict__ inB, u16* __restrict__ outB, int n8B,
    const float* __restrict__ inC, u16* __restrict__ outC, int n8C,
    int bA, int bB) {
  const int bx = blockIdx.x, tid = threadIdx.x;
  if (bx < bA) {
    const int i = bx * 256 + tid;
    if (i < n8A) cvt_store8(outA + (long)i * 8, inA + (long)i * 8);
  } else if (bx < bA + bB) {
    const int i = (bx - bA) * 256 + tid;
    if (i < n8B) cvt_store8(outB + (long)i * 8, inB + (long)i * 8);
  } else {
    const int i = (bx - bA - bB) * 256 + tid;
    if (i < n8C) cvt_store8(outC + (long)i * 8, inC + (long)i * 8);
  }
}

// ---------------------------------------------------------------------------
// NT GEMM, m97-style: A,B bf16, global_load_lds w=16, unpadded LDS,
// BM x BN tile, 2-barrier K-loop.
// R24: gemm0 reverted to BM=128 (R23's BM=64 raised occupancy 15->29% but
// REGRESSED 48->59us: per-block overhead (2x barriers/row, halved
// MFMA-per-staging amortization, conflicts 3.1->4.7M) exceeded the
// latency-hiding gain. Third confirmation: occupancy-raising restructures
// lose on this structure. Do not revisit.)
// gemm0 (qkv): BM=128, BN=128, grid (24,32) = 768 = 3 blk/CU.
// gemm1 (proj): BM=128, BN=64, grid (16,32) = 512 = 2 blk/CU.
// Epilogue trig kept on-device (R21: table version SLOWER, scattered loads).
// MODE 0: scatter -> q,k [B][H][T][DH] with RoPE FUSED; V TRANSPOSED
//         [B][H][DH][T]. MODE 1: f32 row-major out.
// ---------------------------------------------------------------------------
template <int MODE, int BN, int BM>
__global__ __launch_bounds__(256) void gemm_nt(
    const u16* __restrict__ A, const u16* __restrict__ Bw,
    const float* __restrict__ bias, float* __restrict__ out,
    u16* __restrict__ q_ws, u16* __restrict__ k_ws, u16* __restrict__ v_ws,
    int M, int N, int K) {
  constexpr int NTN = BN / 32;          // n-tiles per wave (4 or 2)
  constexpr int WNS = BN / 2;           // per-wave n-span (64 or 32)
  constexpr int MT = BM / 32;           // m-tiles per wave (4 or 2)
  constexpr int WMS = BM / 2;           // per-wave m-span (64 or 32)
  __shared__ __align__(16) u16 As[BM * 32];
  __shared__ __align__(16) u16 Bs[BN * 32];
  const int tid = threadIdx.x;
  const int wave = tid >> 6, lane = tid & 63;
  const int quad = lane >> 4, l16 = lane & 15;
  const int wm = wave & 1, wn = wave >> 1;
  const int m0 = blockIdx.y * BM, n0 = blockIdx.x * BN;
  const int lrow = lane >> 2;           // 0..15
  const int lcol = (lane & 3) * 8;      // 8-elem chunk offset

  f32x4 acc[MT][NTN] = {};

  const u16* Ag = A + (long)(m0 + wave * 16 + lrow) * K + lcol;
  const u16* Bg = Bw + (long)(n0 + wave * 16 + lrow) * K + lcol;
  u16* Al = &As[(wave * 16 + lrow) * 32 + lcol];
  u16* Bl = &Bs[(wave * 16 + lrow) * 32 + lcol];

  for (int k0 = 0; k0 < K; k0 += 32) {
    __syncthreads();
    gld_lds16(Ag + k0, Al);
    if constexpr (BM == 128) gld_lds16(Ag + (long)64 * K + k0, Al + 64 * 32);
    gld_lds16(Bg + k0, Bl);
    if constexpr (BN == 128) gld_lds16(Bg + (long)64 * K + k0, Bl + 64 * 32);
    __syncthreads();
    bf16x8 af[MT], bfr[NTN];
#pragma unroll
    for (int mt = 0; mt < MT; mt++)
      af[mt] = ld_frag(&As[(wm * WMS + mt * 16 + l16) * 32 + quad * 8]);
#pragma unroll
    for (int nt = 0; nt < NTN; nt++)
      bfr[nt] = ld_frag(&Bs[(wn * WNS + nt * 16 + l16) * 32 + quad * 8]);
#pragma unroll
    for (int mt = 0; mt < MT; mt++)
#pragma unroll
      for (int nt = 0; nt < NTN; nt++)
        acc[mt][nt] = __builtin_amdgcn_mfma_f32_16x16x32_bf16(af[mt], bfr[nt],
                                                              acc[mt][nt], 0, 0, 0);
  }

  if constexpr (MODE == 1) {
#pragma unroll
    for (int nt = 0; nt < NTN; nt++) {
      const int col = n0 + wn * WNS + nt * 16 + l16;
      const float bv = bias[col];
#pragma unroll
      for (int mt = 0; mt < MT; mt++) {
        const int rbase = m0 + wm * WMS + mt * 16 + quad * 4;
#pragma unroll
        for (int r = 0; r < 4; r++)
          out[(long)(rbase + r) * N + col] = acc[mt][nt][r] + bv;
      }
    }
  } else {
    const int which = n0 >> 10;  // block-uniform: 0=q 1=k 2=v
#pragma unroll
    for (int np = 0; np < 2; np++) {  // pair (np, np+2): head-dims dh, dh+32
      const int col1 = n0 + wn * 64 + np * 16 + l16;
      const int rem = col1 & 1023;
      const int h = rem >> 6, dh = rem & 63;     // dh < 32 always
      const float bv1 = bias[col1], bv2 = bias[col1 + 32];
      if (which == 2) {  // V: no rope, transposed store [B][H][DH][T]
#pragma unroll
        for (int mt = 0; mt < MT; mt++) {
          const int rbase = m0 + wm * WMS + mt * 16 + quad * 4;
          const int b = rbase >> 11;
#pragma unroll
          for (int r = 0; r < 4; r++) {
            const int t = (rbase + r) & (T_SEQ - 1);
            const long vb = (((long)(b * NH + h)) * DH) * T_SEQ + t;
            v_ws[vb + (long)dh * T_SEQ] = f2bf(acc[mt][np][r] + bv1);
            v_ws[vb + (long)(dh + 32) * T_SEQ] = f2bf(acc[mt][np + 2][r] + bv2);
          }
        }
      } else {  // q or k: fused RoPE (+1/8 score scale folded into q)
        const float invf = exp2f(-(float)dh * 0.41524101186092045f);
        const float cD = cosf(invf), sD = sinf(invf);  // per-row angle step
        u16* dst = (which == 0) ? q_ws : k_ws;
        const float sc = (which == 0) ? 0.125f : 1.0f;
#pragma unroll
        for (int mt = 0; mt < MT; mt++) {
          const int rbase = m0 + wm * WMS + mt * 16 + quad * 4;
          const int b = rbase >> 11;
          const int t0 = rbase & (T_SEQ - 1);
          float c = cosf((float)t0 * invf), s = sinf((float)t0 * invf);
#pragma unroll
          for (int r = 0; r < 4; r++) {
            const float v1 = acc[mt][np][r] + bv1;
            const float v2 = acc[mt][np + 2][r] + bv2;
            const float o1 = (v1 * c - v2 * s) * sc;
            const float o2 = (v2 * c + v1 * s) * sc;
            const long ib = (((long)(b * NH + h)) * T_SEQ + (t0 + r)) * DH;
            dst[ib + dh] = f2bf(o1);
            dst[ib + dh + 32] = f2bf(o2);
            const float cn = c * cD - s * sD;   // advance angle by invf
            s = s * cD + c * sD;
            c = cn;
          }
        }
      }
    }
  }
}

// ---------------------------------------------------------------------------
// Flash attention (causal). R24 = R18 structure + Vt stride 140 (kept from
//  R23 for isolated measurement: gemm0's 59us masked attn in R23's top-5,
//  so the conflict counter was unreadable. With gemm0 back at ~48, attn
//  resurfaces. Decision rule: conflicts < 5M and dur <= 50.6 -> bank-fix
//  banked; conflicts still 6.49M or dur > 51.2 -> revert stride to 136).
//  Bank math: Vt stride 136 = 68 dw = 4 (mod 32) -> PV ds_read_b64 ~4-way
//  aliased; stride 140 = 70 dw = 6 (mod 32) -> all 16 rows distinct banks.
//  Everything else frozen from R18 (best 50.5-51.2us): T5 setprio, T14
//  split staging, fixed-shift softmax, cvt_pk.
//  FAILED grafts (do not revisit): R15 32-row blocks; R17 de-LDS;
//  R19 512-thr 8-wave (spill); R20 grid key-split; R21 RoPE table;
//  R23 gemm0 BM=64.
// ---------------------------------------------------------------------------
__global__ __launch_bounds__(256, 4) void attn_kernel(const u16* __restrict__ q,
                                                      const u16* __restrict__ k,
                                                      const u16* __restrict__ v,
                                                      u16* __restrict__ o) {
  __shared__ __align__(16) u16 Ks[128 * 72];
  __shared__ __align__(16) u16 Vt[64 * 140];
  const int tid = threadIdx.x;
  const int wave = tid >> 6, lane = tid & 63;
  const int quad = lane >> 4, l16 = lane & 15;
  const int bh = blockIdx.x;     // 0..31  (XCD = const per bh)
  const int y = blockIdx.y;      // 0..31
  const int kk = y >> 3, a = y & 7;   // stride-8-proof complementary map
  const int qt = (kk == 0) ? (2 * a)
               : (kk == 1) ? (31 - 2 * a)
               : (kk == 2) ? (2 * a + 1)
                           : (30 - 2 * a);
  const long base = (long)bh * T_SEQ * DH;
  const int b = bh >> 4, h = bh & 15;

  const int q0 = qt * 64;
  const int qrow = q0 + wave * 16 + l16;   // this lane's q-row
  bf16x8 bq0, bq1;                         // Q as B-fragment
  {
    const u16* qr = q + base + (long)qrow * DH + quad * 8;
    bq0 = ld_frag(qr);
    bq1 = ld_frag(qr + 32);
  }
  float lst = 0.f;
  f32x4 oacc[4] = {};    // O^T: col=q(l16), row=d=ont*16+quad*4+r
  const int nkt = (q0 + 64 + 127) >> 7;    // 128-key staged tiles

  // staging geometry (lane-constant)
  const int k_rr = tid >> 3;          // + p*32, rows of K tile
  const int k_cc = (tid & 7) * 8;     // 16B col chunk
  const int v_d  = tid >> 4;          // + p*16, head-dim rows of V^T
  const int v_cc = (tid & 15) * 8;    // 16B col chunk along T
  const u16* kbase = k + base;
  const u16* vbase = v + base;

  i32x4 kreg[4], vreg[4];
  // prologue: load tile 0 into regs, write to LDS
#pragma unroll
  for (int p = 0; p < 4; p++) {
    kreg[p] = ld16(kbase + (long)(k_rr + p * 32) * DH + k_cc);
    vreg[p] = ld16(vbase + (long)(v_d + p * 16) * T_SEQ + v_cc);
  }
#pragma unroll
  for (int p = 0; p < 4; p++) {
    st16(&Ks[(k_rr + p * 32) * 72 + k_cc], kreg[p]);
    st16(&Vt[(v_d + p * 16) * 140 + v_cc], vreg[p]);
  }
  __syncthreads();

  for (int kt = 0; kt < nkt; kt++) {
    const int key0 = kt * 128;
    const bool last = (kt == nkt - 1);

    // T14(a): issue next tile's global loads NOW; latency hides under compute
    if (!last) {
      const int kn = key0 + 128;
#pragma unroll
      for (int p = 0; p < 4; p++) {
        kreg[p] = ld16(kbase + (long)kn * DH + (long)(k_rr + p * 32) * DH + k_cc);
        vreg[p] = ld16(vbase + kn + (long)(v_d + p * 16) * T_SEQ + v_cc);
      }
    }

#pragma unroll
    for (int hh = 0; hh < 2; hh++) {
      if (hh == 1 && last && key0 >= q0) continue;  // fully-masked half
      const int kb = key0 + hh * 64;

      // St sub-tile (batched): sfr[nt][r] = S[kb+nt*16+quad*4+r][qrow]
      f32x4 sfr[4];
      __builtin_amdgcn_s_setprio(1);   // T5: favor MFMA-phase waves
#pragma unroll
      for (int nt = 0; nt < 4; nt++) {
        const int row = hh * 64 + nt * 16 + l16;
        bf16x8 k0f = ld_frag(&Ks[row * 72 + quad * 8]);
        bf16x8 k1f = ld_frag(&Ks[row * 72 + 32 + quad * 8]);
        f32x4 z = {0.f, 0.f, 0.f, 0.f};
        z = __builtin_amdgcn_mfma_f32_16x16x32_bf16(k0f, bq0, z, 0, 0, 0);
        z = __builtin_amdgcn_mfma_f32_16x16x32_bf16(k1f, bq1, z, 0, 0, 0);
        sfr[nt] = z;
      }
      __builtin_amdgcn_s_setprio(0);

      if (last) {  // causal mask (diagonal staged tile only)
#pragma unroll
        for (int nt = 0; nt < 4; nt++) {
          const int keyb = kb + nt * 16 + quad * 4;
#pragma unroll
          for (int r = 0; r < 4; r++)
            sfr[nt][r] = (keyb + r <= qrow) ? sfr[nt][r] : -1e30f;
        }
      }

      // P^T = exp2(S*log2e - 46.166)  (fixed shift m=32; masked -> 0)
      float rsum = 0.f;
      s16x4 pf[4];
#pragma unroll
      for (int nt = 0; nt < 4; nt++) {
        bf16v4 pv;
#pragma unroll
        for (int r = 0; r < 4; r++) {
          const float p =
              exp2f(__builtin_fmaf(sfr[nt][r], 1.44269504f, -46.166241f));
          rsum += p;
          pv[r] = (__bf16)p;   // v_cvt_pk_bf16_f32 (RNE)
        }
        pf[nt] = __builtin_bit_cast(s16x4, pv);
      }
      rsum += __shfl_xor(rsum, 16, 64);
      rsum += __shfl_xor(rsum, 32, 64);
      lst += rsum;

      // O^T += V^T · P^T  (A-frag: Vt[d][k], 8B loads, ~2-way banks @140)
      __builtin_amdgcn_s_setprio(1);   // T5
#pragma unroll
      for (int ont = 0; ont < 4; ont++) {
        const u16* vrow = &Vt[(ont * 16 + l16) * 140 + hh * 64 + quad * 4];
#pragma unroll
        for (int nt = 0; nt < 4; nt++) {
          s16x4 vf = ld8(vrow + nt * 16);
          oacc[ont] = __builtin_amdgcn_mfma_f32_16x16x16bf16_1k(vf, pf[nt],
                                                                oacc[ont], 0, 0, 0);
        }
      }
      __builtin_amdgcn_s_setprio(0);
    }

    // T14(b): everyone done reading LDS -> overwrite with prefetched tile
    if (!last) {
      __syncthreads();
#pragma unroll
      for (int p = 0; p < 4; p++) {
        st16(&Ks[(k_rr + p * 32) * 72 + k_cc], kreg[p]);
        st16(&Vt[(v_d + p * 16) * 140 + v_cc], vreg[p]);
      }
      __syncthreads();
    }
  }

  // epilogue: O^T/l -> attn_out ws [B][T][C] bf16; 4 consecutive d per quad
  const float inv_l = 1.f / lst;
  u16* orow = o + ((long)(b * T_SEQ + qrow)) * DM + h * DH + quad * 4;
#pragma unroll
  for (int ont = 0; ont < 4; ont++) {
    bf16v4 t4;
#pragma unroll
    for (int r = 0; r < 4; r++) t4[r] = (__bf16)(oacc[ont][r] * inv_l);
    __builtin_memcpy(orow + ont * 16, &t4, 8);
  }
}

// ---------------------------------------------------------------------------
extern "C" void kernel_launch(void* const* d_in, const int* in_sizes, int n_in,
                              void* d_out, int out_size, void* d_ws, size_t ws_size,
                              hipStream_t stream) {
  const float* x      = (const float*)d_in[0];
  const float* qkv_w  = (const float*)d_in[1];
  const float* qkv_b  = (const float*)d_in[2];
  const float* proj_w = (const float*)d_in[3];
  const float* proj_b = (const float*)d_in[4];
  float* out = (float*)d_out;

  u16* ws = (u16*)d_ws;
  const long per = (long)NB * NH * T_SEQ * DH;  // 4,194,304 elems
  u16* q_ws = ws;
  u16* k_ws = ws + per;
  u16* v_ws = ws + 2 * per;              // transposed [B][H][DH][T]
  u16* ao_ws = ws + 3 * per;             // aliases x_bf (x dead after gemm0)
  u16* x_bf  = ws + 3 * per;
  u16* w_bf  = ws + 4 * per;             // qkv_w_bf (gemm0)
  const size_t base_bytes = (size_t)(4 * per + 3 * DM * DM) * 2;  // 39.85 MB
  u16* pw_bf = (u16*)((char*)d_ws + base_bytes);                  // 2 MB
  const size_t need = base_bytes + (size_t)DM * DM * 2;

  dim3 blk(256);
  if (ws_size >= need) {
    // R22 front: one kernel converts x, qkv_w, proj_w; no late cvt.
    cvt3_f32_bf16<<<2048 + 1536 + 512, blk, 0, stream>>>(
        x, x_bf, (int)(per / 8), qkv_w, w_bf, 3 * DM * DM / 8,
        proj_w, pw_bf, DM * DM / 8, 2048, 1536);
    gemm_nt<0, 128, 128><<<dim3(24, 32), blk, 0, stream>>>(
        x_bf, w_bf, qkv_b, nullptr, q_ws, k_ws, v_ws, 4096, 3072, 1024);
    attn_kernel<<<dim3(32, 32), blk, 0, stream>>>(q_ws, k_ws, v_ws, ao_ws);
    gemm_nt<1, 64, 128><<<dim3(16, 32), blk, 0, stream>>>(
        ao_ws, pw_bf, proj_b, out, nullptr, nullptr, nullptr, 4096, 1024, 1024);
  } else {
    // fallback (R18-style ordering)
    cvt2_f32_bf16<<<2048 + 1536, blk, 0, stream>>>(
        x, x_bf, (int)(per / 8), qkv_w, w_bf, 3 * DM * DM / 8, 2048);
    gemm_nt<0, 128, 128><<<dim3(24, 32), blk, 0, stream>>>(
        x_bf, w_bf, qkv_b, nullptr, q_ws, k_ws, v_ws, 4096, 3072, 1024);
    attn_kernel<<<dim3(32, 32), blk, 0, stream>>>(q_ws, k_ws, v_ws, ao_ws);
    cvt_f32_bf16<<<512, blk, 0, stream>>>(proj_w, w_bf, DM * DM / 8);
    gemm_nt<1, 64, 128><<<dim3(16, 32), blk, 0, stream>>>(
        ao_ws, w_bf, proj_b, out, nullptr, nullptr, nullptr, 4096, 1024, 1024);
  }
}